// Round 2
// 412.359 us; speedup vs baseline: 1.0243x; 1.0243x over previous
//
#include <hip/hip_runtime.h>

// Problem constants (from the reference):
//   B=8, H=32, W=32, T=4, BS=3, D=768, SMAX=2, P=2560
// Output [B,H,W,T,BS,D] float32. Every (y,x,t) cell is covered by exactly
// one patch (blocks tile the grid), so a direct scatter writes every output
// element exactly once -> no zero-init of d_out needed.
//
// v2b: non-temporal loads/stores (fixed: the builtin needs a native clang
// ext_vector_type, not HIP_vector_type). Working set 189 MB read + 302 MB
// write, zero reuse, ~15x aggregate L2 -> stream past the caches.

constexpr int H_ = 32;
constexpr int W_ = 32;
constexpr int T_ = 4;
constexpr int BS_ = 3;
constexpr int D_ = 768;
constexpr int CD  = BS_ * D_;   // 2304 floats per cell
constexpr int CD4 = CD / 4;     // 576 float4 per cell
constexpr int BLOCK = 192;      // 3 waves; 576 / 192 == 3 float4 per thread

typedef float f4 __attribute__((ext_vector_type(4)));

__global__ __launch_bounds__(BLOCK) void apt_scatter_kernel_nt(
    const f4* __restrict__ tok,   // [B*P, CD4] f4
    const int4* __restrict__ pos, // [B*P] (y, x, size, t)
    f4* __restrict__ out,         // [B,H,W,T, CD4] f4
    int P)
{
    const int bp = blockIdx.x;              // b*P + p
    const int b  = bp / P;

    const int4 q = pos[bp];                 // uniform load (same addr all lanes)
    const int y = q.x, x = q.y, size = q.z, t = q.w;

    const f4* __restrict__ src = tok + (long)bp * CD4;
    const long cell_stride_y = (long)W_ * T_ * CD4;
    const long cell_stride_x = (long)T_ * CD4;
    const long base0 = ((((long)b * H_ + y) * W_ + x) * T_ + t) * CD4;

    const int tid = threadIdx.x;

    if (size == 1) {
        f4* __restrict__ dst = out + base0;
        #pragma unroll
        for (int k = 0; k < CD4 / BLOCK; ++k) {
            const int i = tid + k * BLOCK;
            const f4 v = __builtin_nontemporal_load(&src[i]);
            __builtin_nontemporal_store(v, &dst[i]);
        }
    } else {
        // coarse 2x2 patch: broadcast token to 4 cells
        f4* __restrict__ d00 = out + base0;
        f4* __restrict__ d01 = out + base0 + cell_stride_x;
        f4* __restrict__ d10 = out + base0 + cell_stride_y;
        f4* __restrict__ d11 = out + base0 + cell_stride_y + cell_stride_x;
        #pragma unroll
        for (int k = 0; k < CD4 / BLOCK; ++k) {
            const int i = tid + k * BLOCK;
            const f4 v = __builtin_nontemporal_load(&src[i]);
            __builtin_nontemporal_store(v, &d00[i]);
            __builtin_nontemporal_store(v, &d01[i]);
            __builtin_nontemporal_store(v, &d10[i]);
            __builtin_nontemporal_store(v, &d11[i]);
        }
    }
}

extern "C" void kernel_launch(void* const* d_in, const int* in_sizes, int n_in,
                              void* d_out, int out_size, void* d_ws, size_t ws_size,
                              hipStream_t stream) {
    const f4*   tok = (const f4*)d_in[0];     // [B, P*BS, D] f32
    const int4* pos = (const int4*)d_in[1];   // [B, P, 4] i32

    const int Bn = 8;
    const int P  = in_sizes[1] / (Bn * 4);    // 2560

    const int grid = Bn * P;                  // 20480 blocks
    apt_scatter_kernel_nt<<<grid, BLOCK, 0, stream>>>(tok, pos, (f4*)d_out, P);
}